// Round 6
// baseline (537.749 us; speedup 1.0000x reference)
//
#include <hip/hip_runtime.h>
#include <hip/hip_fp16.h>

typedef _Float16 f16;
typedef _Float16 f16x8 __attribute__((ext_vector_type(8)));
typedef _Float16 f16x4 __attribute__((ext_vector_type(4)));
typedef float    f32x4 __attribute__((ext_vector_type(4)));
typedef float    f32x2 __attribute__((ext_vector_type(2)));

#define NEGV -1000000000.0f
// B=2, S=2048, H=1024, NH=16, D=64 hard-coded throughout.

// ---------------- fp32 -> f16 convert (3 tensors batched via blockIdx.y) ----
__global__ __launch_bounds__(256) void cvt3(const float* __restrict__ a,
                                            const float* __restrict__ b,
                                            const float* __restrict__ c,
                                            f16* __restrict__ out, int per) {
  const float* src = blockIdx.y == 0 ? a : (blockIdx.y == 1 ? b : c);
  int i = (blockIdx.x * 256 + threadIdx.x) * 4;
  if (i >= per) return;
  f32x4 v = *(const f32x4*)(src + i);
  f16x4 h; h[0]=(f16)v[0]; h[1]=(f16)v[1]; h[2]=(f16)v[2]; h[3]=(f16)v[3];
  *(f16x4*)(out + (size_t)blockIdx.y * per + i) = h;
}

// ---------------- mask int32 -> bitmask (1 bit per entry) -------------------
__global__ __launch_bounds__(256) void pack_mask(const int* __restrict__ m,
                                                 unsigned* __restrict__ bits) {
  size_t i = (size_t)blockIdx.x * 256 + threadIdx.x;
  unsigned long long b = __ballot(m[i] != 0);
  int lane = threadIdx.x & 63;
  if (lane == 0)       bits[i >> 5] = (unsigned)b;
  else if (lane == 32) bits[i >> 5] = (unsigned)(b >> 32);
}

// ---------------- async global->LDS helper ----------------------------------
__device__ inline void gld16(const void* g, void* l) {
  __builtin_amdgcn_global_load_lds((const __attribute__((address_space(1))) void*)g,
                                   (__attribute__((address_space(3))) void*)l, 16, 0, 0);
}

// ---------------- projection GEMM: Y = X @ W^T ------------------------------
// X: [4096][1024] f16 row-major, W: [1024(n)][1024(k)] f16 row-major.
// z=0 -> Qh, z=1 -> Kh, z=2 -> Vn; all [bh][s][64] (coalesced writes).
__global__ __launch_bounds__(256) void gemm_proj(const f16* __restrict__ Xall,
                                                 const f16* __restrict__ Wall,
                                                 f16* __restrict__ Qh,
                                                 f16* __restrict__ Kh,
                                                 f16* __restrict__ Vn) {
  __shared__ f16 lA[4][128][8];   // [kslot][row][8]: conflict-free frag reads
  __shared__ f16 lB[4][128][8];
  const int z = blockIdx.z;
  const f16* A  = Xall + (size_t)z * (4096u * 1024u);
  const f16* Wt = Wall + (size_t)z * (1024u * 1024u);
  f16* Y = (z == 0) ? Qh : (z == 1 ? Kh : Vn);
  const int t = threadIdx.x;
  const int brow = blockIdx.y * 128, bcol = blockIdx.x * 128;
  const int w = t >> 6, l = t & 63;
  const int wr = w >> 1, wc = w & 1;       // 2x2 waves, 64x64 each
  const int lr = l & 15, lg = l >> 4;
  f32x4 acc[4][4] = {};

  for (int k0 = 0; k0 < 1024; k0 += 32) {
#pragma unroll
    for (int j = 0; j < 2; j++) {
      const int p = j * 4096 + t * 16;        // byte offset in 8KB tile
      const int ks = p >> 11, row = (p >> 4) & 127;
      gld16(A  + (size_t)(brow + row) * 1024 + k0 + ks * 8, (char*)lA + p);
      gld16(Wt + (size_t)(bcol + row) * 1024 + k0 + ks * 8, (char*)lB + p);
    }
    __syncthreads();
    f16x8 af[4], bf[4];
#pragma unroll
    for (int mi = 0; mi < 4; mi++) af[mi] = *(const f16x8*)&lA[lg][wr * 64 + mi * 16 + lr][0];
#pragma unroll
    for (int ni = 0; ni < 4; ni++) bf[ni] = *(const f16x8*)&lB[lg][wc * 64 + ni * 16 + lr][0];
#pragma unroll
    for (int mi = 0; mi < 4; mi++)
#pragma unroll
      for (int ni = 0; ni < 4; ni++)
        acc[mi][ni] = __builtin_amdgcn_mfma_f32_16x16x32_f16(af[mi], bf[ni], acc[mi][ni], 0, 0, 0);
    __syncthreads();
  }

  const int mb0 = brow + wr * 64, nb0 = bcol + wc * 64;
#pragma unroll
  for (int mi = 0; mi < 4; mi++)
#pragma unroll
    for (int ni = 0; ni < 4; ni++)
#pragma unroll
      for (int j = 0; j < 4; j++) {
        const int m = mb0 + mi * 16 + lg * 4 + j;   // token index (b*2048+s)
        const int n = nb0 + ni * 16 + lr;           // h*64+d
        const int bb = m >> 11, s = m & 2047;
        const int h = n >> 6, d = n & 63;
        Y[((((size_t)bb * 16 + h) * 2048 + s) << 6) + d] = (f16)acc[mi][ni][j];
      }
}

// ---------------- V transpose: [bh][s][64] -> [bh][d][2048] -----------------
__global__ __launch_bounds__(512) void transposeV(const f16* __restrict__ Vn,
                                                  f16* __restrict__ VhT) {
  const int bh = blockIdx.y, s0 = blockIdx.x * 64;
  const int t = threadIdx.x, l = t & 63, w = t >> 6;
  const f16x8 v = *(const f16x8*)(Vn + (((size_t)bh * 2048 + s0 + l) << 6) + w * 8);
#pragma unroll
  for (int e = 0; e < 8; e++)
    VhT[(((size_t)bh * 64 + w * 8 + e) << 11) + s0 + l] = v[e];
}

// ---------------- fused attention v6: barrier-free --------------------------
// 512 blocks, 8 waves each; every wave owns 16 q-rows end-to-end. K and V^T
// are loaded DIRECTLY from global (L2-resident; each bh pinned to one XCD via
// the wg decode). No __syncthreads anywhere: the only ordering is the wave-
// private P round-trip through LDS (in-order lgkmcnt). LDS = 32 KB (P only).
__device__ inline char* swzW(char* wb, int row, int col) {
  return wb + row * 256 + ((col * 2) ^ ((row & 7) << 4));
}

__global__ __launch_bounds__(512, 4) void attn_fused(const f16* __restrict__ Qh,
                                                     const f16* __restrict__ Kh,
                                                     const f16* __restrict__ VhT,
                                                     const unsigned* __restrict__ mbits,
                                                     float* __restrict__ attn,
                                                     float* __restrict__ ctx) {
  __shared__ char Pw[8 * 4096];     // 32 KB: per-wave P tile [16][128] f16 swz
  const int wg = blockIdx.x;
  const int bh = ((wg & 7) << 2) | (wg >> 7);    // 16 blocks/bh on ONE XCD
  const int qg = (wg >> 3) & 15;
  const int b = bh >> 4, h = bh & 15;
  const int t = threadIdx.x, w = t >> 6, l = t & 63;
  const int lr = l & 15, lg = l >> 4;
  const int qr = qg * 128 + w * 16;          // this wave's 16 q-rows
  char* wb = Pw + w * 4096;

  const f16* Kbase = Kh + ((size_t)bh << 17);          // [2048][64]
  const f16* Vbase = VhT + ((size_t)bh << 17);         // [64][2048]

  // Q fragments (once)
  const f16* qp = Qh + (((size_t)bh * 2048 + qr + lr) << 6) + lg * 8;
  const f16x8 aq0 = *(const f16x8*)qp;
  const f16x8 aq1 = *(const f16x8*)(qp + 32);

  const unsigned* mrow0 = mbits + ((size_t)b * 2048 + qr + lg * 4) * 64;

  // =================== LOOP 1: exp-sums (no LDS, no barriers) ===============
  float sj[4] = {0.f, 0.f, 0.f, 0.f};
  for (int t16 = 0; t16 < 16; t16++) {
    const int kb = t16 * 128;
    uint4 mrow[4];
#pragma unroll
    for (int j = 0; j < 4; j++) mrow[j] = *(const uint4*)(mrow0 + j * 64 + (kb >> 5));
    const f16* kt = Kbase + ((size_t)(kb + lr) << 6) + lg * 8;
#pragma unroll
    for (int nf = 0; nf < 8; nf++) {
      const f16* kp = kt + (nf << 10);       // += nf*16 rows
      const f16x8 bk0 = *(const f16x8*)kp;
      const f16x8 bk1 = *(const f16x8*)(kp + 32);
      f32x4 s4 = {};
      s4 = __builtin_amdgcn_mfma_f32_16x16x32_f16(aq0, bk0, s4, 0, 0, 0);
      s4 = __builtin_amdgcn_mfma_f32_16x16x32_f16(aq1, bk1, s4, 0, 0, 0);
      const unsigned bp = ((nf & 1) << 4) + lr;
#pragma unroll
      for (int j = 0; j < 4; j++) {
        const unsigned bit = (((const unsigned*)&mrow[j])[nf >> 1] >> bp) & 1u;
        sj[j] += bit ? __expf(s4[j]) : 0.f;
      }
    }
  }
  float SI[4];
#pragma unroll
  for (int j = 0; j < 4; j++) {
    float s = sj[j];
#pragma unroll
    for (int o = 1; o < 16; o <<= 1) s += __shfl_xor(s, o, 64);
    SI[j] = 1.0f / s;
  }

  // =================== LOOP 2: normalize, P->LDS, PV, vectorized stores =====
  f32x4 acc[4] = {};
  float* abase = attn + (((size_t)bh * 2048 + qr) << 11);   // [16 rows][2048]
  const int srow = l >> 3, scol = (l & 7) * 4;              // store map: 8 lanes/row
  for (int t16 = 0; t16 < 16; t16++) {
    const int kb = t16 * 128;
    uint4 mrow[4];
#pragma unroll
    for (int j = 0; j < 4; j++) mrow[j] = *(const uint4*)(mrow0 + j * 64 + (kb >> 5));
    const f16* kt = Kbase + ((size_t)(kb + lr) << 6) + lg * 8;
#pragma unroll
    for (int nf = 0; nf < 8; nf++) {
      const f16* kp = kt + (nf << 10);
      const f16x8 bk0 = *(const f16x8*)kp;
      const f16x8 bk1 = *(const f16x8*)(kp + 32);
      f32x4 s4 = {};
      s4 = __builtin_amdgcn_mfma_f32_16x16x32_f16(aq0, bk0, s4, 0, 0, 0);
      s4 = __builtin_amdgcn_mfma_f32_16x16x32_f16(aq1, bk1, s4, 0, 0, 0);
      const unsigned bp = ((nf & 1) << 4) + lr;
#pragma unroll
      for (int j = 0; j < 4; j++) {
        const unsigned bit = (((const unsigned*)&mrow[j])[nf >> 1] >> bp) & 1u;
        const float pj = bit ? __expf(s4[j]) * SI[j] : 0.f;
        *(f16*)swzW(wb, lg * 4 + j, nf * 16 + lr) = (f16)pj;  // P for PV + store
      }
    }
    // PV on this tile: P from wave-private LDS, V^T direct from global (L2).
#pragma unroll
    for (int kk = 0; kk < 4; kk++) {
      const f16x8 pa = *(const f16x8*)swzW(wb, lr, kk * 32 + lg * 8);
#pragma unroll
      for (int nf = 0; nf < 4; nf++) {
        const f16x8 bv = *(const f16x8*)(Vbase + (((size_t)(nf * 16 + lr)) << 11) + kb + kk * 32 + lg * 8);
        acc[nf] = __builtin_amdgcn_mfma_f32_16x16x32_f16(pa, bv, acc[nf], 0, 0, 0);
      }
    }
    // attn stores: readback P, f32x4; 8 lanes span 128B contiguous per row.
#pragma unroll
    for (int h2 = 0; h2 < 2; h2++) {
      const int row = srow + h2 * 8;
      float* arow = abase + ((size_t)row << 11) + kb + scol;
#pragma unroll
      for (int u = 0; u < 4; u++) {
        const f16x4 p4 = *(const f16x4*)swzW(wb, row, scol + u * 32);
        f32x4 o;
#pragma unroll
        for (int e = 0; e < 4; e++) o[e] = (float)p4[e];
        *(f32x4*)(arow + u * 32) = o;
      }
    }
  }

  // ctx write: rows qr+lg*4+j, cols h*64 + nf*16+lr
#pragma unroll
  for (int nf = 0; nf < 4; nf++)
#pragma unroll
    for (int j = 0; j < 4; j++)
      ctx[((size_t)b * 2048 + qr + lg * 4 + j) * 1024 + h * 64 + nf * 16 + lr] = acc[nf][j];
}

// ---------------- residual + LayerNorm (in place on d_out) ------------------
__global__ __launch_bounds__(256) void ln_res(const float* __restrict__ qres,
                                              const float* __restrict__ gamma,
                                              const float* __restrict__ beta,
                                              float* __restrict__ io) {
  const int tok = blockIdx.x;
  const int t = threadIdx.x;
  float* rowp = io + (size_t)tok * 1024;
  const float* qp = qres + (size_t)tok * 1024;
  const f32x4 c = *(const f32x4*)(rowp + t * 4);
  const f32x4 r = *(const f32x4*)(qp + t * 4);
  f32x4 vals;
  float s = 0.f, s2 = 0.f;
#pragma unroll
  for (int e = 0; e < 4; e++) { float x = c[e] + r[e]; vals[e] = x; s += x; s2 += x * x; }
#pragma unroll
  for (int o = 1; o < 64; o <<= 1) { s += __shfl_xor(s, o, 64); s2 += __shfl_xor(s2, o, 64); }
  __shared__ float rs[4][2];
  const int w = t >> 6;
  if ((t & 63) == 0) { rs[w][0] = s; rs[w][1] = s2; }
  __syncthreads();
  s  = rs[0][0] + rs[1][0] + rs[2][0] + rs[3][0];
  s2 = rs[0][1] + rs[1][1] + rs[2][1] + rs[3][1];
  const float mu = s * (1.f / 1024.f);
  const float var = s2 * (1.f / 1024.f) - mu * mu;
  const float rstd = rsqrtf(var + 1e-6f);
  const f32x4 g  = *(const f32x4*)(gamma + t * 4);
  const f32x4 be = *(const f32x4*)(beta + t * 4);
  f32x4 o;
#pragma unroll
  for (int e = 0; e < 4; e++) o[e] = (vals[e] - mu) * rstd * g[e] + be[e];
  *(f32x4*)(rowp + t * 4) = o;
}

// ---------------- host ------------------------------------------------------
extern "C" void kernel_launch(void* const* d_in, const int* in_sizes, int n_in,
                              void* d_out, int out_size, void* d_ws, size_t ws_size,
                              hipStream_t stream) {
  const float* q     = (const float*)d_in[0];
  const float* k     = (const float*)d_in[1];
  const float* v     = (const float*)d_in[2];
  const int*   mask  = (const int*)d_in[3];
  const float* Wq    = (const float*)d_in[4];
  const float* Wk    = (const float*)d_in[5];
  const float* Wv    = (const float*)d_in[6];
  const float* gamma = (const float*)d_in[7];
  const float* beta  = (const float*)d_in[8];
  float* out  = (float*)d_out;
  float* attn = out + (size_t)4194304;       // B*S*H
  const size_t MB = 1u << 20;
  char* ws = (char*)d_ws;

  f16 *x16, *W16, *Qh, *Kh, *Vn, *VhT; unsigned* mb;
  if (ws_size >= 63 * MB) {
    x16 = (f16*)ws;              W16 = (f16*)(ws + 24 * MB);
    Qh  = (f16*)(ws + 30 * MB);  Kh  = (f16*)(ws + 38 * MB);
    Vn  = (f16*)(ws + 46 * MB);  VhT = (f16*)(ws + 54 * MB);
    mb  = (unsigned*)(ws + 62 * MB);
  } else {
    // stage f16 inputs + Vn in the (not-yet-written) attn region of d_out
    x16 = (f16*)attn;            W16 = (f16*)((char*)attn + 24 * MB);
    Vn  = (f16*)((char*)attn + 30 * MB);
    Qh  = (f16*)ws;              Kh  = (f16*)(ws + 8 * MB);
    VhT = (f16*)(ws + 16 * MB);  mb  = (unsigned*)(ws + 24 * MB);
  }

  cvt3<<<dim3(4096, 3), 256, 0, stream>>>(q, k, v, x16, 4194304);
  cvt3<<<dim3(1024, 3), 256, 0, stream>>>(Wq, Wk, Wv, W16, 1048576);
  pack_mask<<<dim3(32768), 256, 0, stream>>>(mask, mb);
  gemm_proj<<<dim3(8, 32, 3), 256, 0, stream>>>(x16, W16, Qh, Kh, Vn);
  transposeV<<<dim3(32, 32), 512, 0, stream>>>(Vn, VhT);
  attn_fused<<<dim3(512), 512, 0, stream>>>(Qh, Kh, VhT, mb, attn, out);
  ln_res<<<dim3(4096), 256, 0, stream>>>(q, gamma, beta, out);
}

// Round 7
// 307.270 us; speedup vs baseline: 1.7501x; 1.7501x over previous
//
#include <hip/hip_runtime.h>
#include <hip/hip_fp16.h>

typedef _Float16 f16;
typedef _Float16 f16x8 __attribute__((ext_vector_type(8)));
typedef _Float16 f16x4 __attribute__((ext_vector_type(4)));
typedef float    f32x4 __attribute__((ext_vector_type(4)));
typedef float    f32x2 __attribute__((ext_vector_type(2)));

#define NEGV -1000000000.0f
// B=2, S=2048, H=1024, NH=16, D=64 hard-coded throughout.

// ---------------- fp32 -> f16 convert (3 tensors batched via blockIdx.y) ----
__global__ __launch_bounds__(256) void cvt3(const float* __restrict__ a,
                                            const float* __restrict__ b,
                                            const float* __restrict__ c,
                                            f16* __restrict__ out, int per) {
  const float* src = blockIdx.y == 0 ? a : (blockIdx.y == 1 ? b : c);
  int i = (blockIdx.x * 256 + threadIdx.x) * 4;
  if (i >= per) return;
  f32x4 v = *(const f32x4*)(src + i);
  f16x4 h; h[0]=(f16)v[0]; h[1]=(f16)v[1]; h[2]=(f16)v[2]; h[3]=(f16)v[3];
  *(f16x4*)(out + (size_t)blockIdx.y * per + i) = h;
}

// ---------------- mask int32 -> bitmask (1 bit per entry) -------------------
__global__ __launch_bounds__(256) void pack_mask(const int* __restrict__ m,
                                                 unsigned* __restrict__ bits) {
  size_t i = (size_t)blockIdx.x * 256 + threadIdx.x;
  unsigned long long b = __ballot(m[i] != 0);
  int lane = threadIdx.x & 63;
  if (lane == 0)       bits[i >> 5] = (unsigned)b;
  else if (lane == 32) bits[i >> 5] = (unsigned)(b >> 32);
}

// ---------------- async global->LDS helper ----------------------------------
__device__ inline void gld16(const void* g, void* l) {
  __builtin_amdgcn_global_load_lds((const __attribute__((address_space(1))) void*)g,
                                   (__attribute__((address_space(3))) void*)l, 16, 0, 0);
}

// ---------------- projection GEMM: Y = X @ W^T ------------------------------
// X: [4096][1024] f16 row-major, W: [1024(n)][1024(k)] f16 row-major.
// z=0 -> Qh, z=1 -> Kh, z=2 -> Vn; all [bh][s][64] (coalesced writes).
__global__ __launch_bounds__(256) void gemm_proj(const f16* __restrict__ Xall,
                                                 const f16* __restrict__ Wall,
                                                 f16* __restrict__ Qh,
                                                 f16* __restrict__ Kh,
                                                 f16* __restrict__ Vn) {
  __shared__ f16 lA[4][128][8];   // [kslot][row][8]: conflict-free frag reads
  __shared__ f16 lB[4][128][8];
  const int z = blockIdx.z;
  const f16* A  = Xall + (size_t)z * (4096u * 1024u);
  const f16* Wt = Wall + (size_t)z * (1024u * 1024u);
  f16* Y = (z == 0) ? Qh : (z == 1 ? Kh : Vn);
  const int t = threadIdx.x;
  const int brow = blockIdx.y * 128, bcol = blockIdx.x * 128;
  const int w = t >> 6, l = t & 63;
  const int wr = w >> 1, wc = w & 1;       // 2x2 waves, 64x64 each
  const int lr = l & 15, lg = l >> 4;
  f32x4 acc[4][4] = {};

  for (int k0 = 0; k0 < 1024; k0 += 32) {
#pragma unroll
    for (int j = 0; j < 2; j++) {
      const int p = j * 4096 + t * 16;        // byte offset in 8KB tile
      const int ks = p >> 11, row = (p >> 4) & 127;
      gld16(A  + (size_t)(brow + row) * 1024 + k0 + ks * 8, (char*)lA + p);
      gld16(Wt + (size_t)(bcol + row) * 1024 + k0 + ks * 8, (char*)lB + p);
    }
    __syncthreads();
    f16x8 af[4], bf[4];
#pragma unroll
    for (int mi = 0; mi < 4; mi++) af[mi] = *(const f16x8*)&lA[lg][wr * 64 + mi * 16 + lr][0];
#pragma unroll
    for (int ni = 0; ni < 4; ni++) bf[ni] = *(const f16x8*)&lB[lg][wc * 64 + ni * 16 + lr][0];
#pragma unroll
    for (int mi = 0; mi < 4; mi++)
#pragma unroll
      for (int ni = 0; ni < 4; ni++)
        acc[mi][ni] = __builtin_amdgcn_mfma_f32_16x16x32_f16(af[mi], bf[ni], acc[mi][ni], 0, 0, 0);
    __syncthreads();
  }

  const int mb0 = brow + wr * 64, nb0 = bcol + wc * 64;
#pragma unroll
  for (int mi = 0; mi < 4; mi++)
#pragma unroll
    for (int ni = 0; ni < 4; ni++)
#pragma unroll
      for (int j = 0; j < 4; j++) {
        const int m = mb0 + mi * 16 + lg * 4 + j;   // token index (b*2048+s)
        const int n = nb0 + ni * 16 + lr;           // h*64+d
        const int bb = m >> 11, s = m & 2047;
        const int h = n >> 6, d = n & 63;
        Y[((((size_t)bb * 16 + h) * 2048 + s) << 6) + d] = (f16)acc[mi][ni][j];
      }
}

// ---------------- V transpose: [bh][s][64] -> [bh][d][2048] -----------------
__global__ __launch_bounds__(512) void transposeV(const f16* __restrict__ Vn,
                                                  f16* __restrict__ VhT) {
  const int bh = blockIdx.y, s0 = blockIdx.x * 64;
  const int t = threadIdx.x, l = t & 63, w = t >> 6;
  const f16x8 v = *(const f16x8*)(Vn + (((size_t)bh * 2048 + s0 + l) << 6) + w * 8);
#pragma unroll
  for (int e = 0; e < 8; e++)
    VhT[(((size_t)bh * 64 + w * 8 + e) << 11) + s0 + l] = v[e];
}

// ---------------- kernel A: exp-sum pass ------------------------------------
// 512 blocks (XCD-pinned: each bh's 16 blocks on one XCD), 8 waves; each wave
// owns 16 q-rows. Staged-K QK^T + masked exp accumulate; writes 1/sum per row.
// Only 16 KB LDS + low VGPR -> better residency than v5's inline loop1.
__global__ __launch_bounds__(512, 4) void sumexp_k(const f16* __restrict__ Qh,
                                                   const f16* __restrict__ Kh,
                                                   const unsigned* __restrict__ mbits,
                                                   float* __restrict__ SIo) {
  __shared__ f16 lK[8][128][8];     // 16 KB
  const int wg = blockIdx.x;
  const int bh = ((wg & 7) << 2) | (wg >> 7);    // 16 blocks/bh on ONE XCD
  const int qg = (wg >> 3) & 15;
  const int b = bh >> 4;
  const int t = threadIdx.x, w = t >> 6, l = t & 63;
  const int lr = l & 15, lg = l >> 4;
  const int qr = qg * 128 + w * 16;

  const int pA = t * 16, pB = 8192 + t * 16;
  const int ksA = pA >> 11, rwA = (pA >> 4) & 127;
  const int ksB = pB >> 11, rwB = (pB >> 4) & 127;
  const f16* Kbase = Kh + ((size_t)bh << 17);

  const f16* qp = Qh + (((size_t)bh * 2048 + qr + lr) << 6) + lg * 8;
  const f16x8 aq0 = *(const f16x8*)qp;
  const f16x8 aq1 = *(const f16x8*)(qp + 32);
  const unsigned* mrow0 = mbits + ((size_t)b * 2048 + qr + lg * 4) * 64;

  float sj[4] = {0.f, 0.f, 0.f, 0.f};
  f16x8 kra = *(const f16x8*)(Kbase + ((size_t)rwA << 6) + ksA * 8);
  f16x8 krb = *(const f16x8*)(Kbase + ((size_t)rwB << 6) + ksB * 8);
  for (int t16 = 0; t16 < 16; t16++) {
    const int kb = t16 * 128;
    __syncthreads();
    *(f16x8*)((char*)lK + pA) = kra;
    *(f16x8*)((char*)lK + pB) = krb;
    __syncthreads();
    uint4 mrow[4];
#pragma unroll
    for (int j = 0; j < 4; j++) mrow[j] = *(const uint4*)(mrow0 + j * 64 + (kb >> 5));
    if (t16 < 15) {
      const f16* nb = Kbase + ((size_t)(kb + 128) << 6);
      kra = *(const f16x8*)(nb + ((size_t)rwA << 6) + ksA * 8);
      krb = *(const f16x8*)(nb + ((size_t)rwB << 6) + ksB * 8);
    }
#pragma unroll
    for (int nf = 0; nf < 8; nf++) {
      f32x4 s4 = {};
      s4 = __builtin_amdgcn_mfma_f32_16x16x32_f16(aq0, *(const f16x8*)&lK[lg][nf * 16 + lr][0], s4, 0, 0, 0);
      s4 = __builtin_amdgcn_mfma_f32_16x16x32_f16(aq1, *(const f16x8*)&lK[4 + lg][nf * 16 + lr][0], s4, 0, 0, 0);
      const unsigned bp = ((nf & 1) << 4) + lr;
#pragma unroll
      for (int j = 0; j < 4; j++) {
        const unsigned bit = (((const unsigned*)&mrow[j])[nf >> 1] >> bp) & 1u;
        sj[j] += bit ? __expf(s4[j]) : 0.f;
      }
    }
  }
#pragma unroll
  for (int j = 0; j < 4; j++) {
#pragma unroll
    for (int o = 1; o < 16; o <<= 1) sj[j] += __shfl_xor(sj[j], o, 64);
  }
  if (lr == 0) {
    float* o = SIo + ((size_t)bh << 11) + qr + lg * 4;
    o[0] = 1.0f / sj[0]; o[1] = 1.0f / sj[1];
    o[2] = 1.0f / sj[2]; o[3] = 1.0f / sj[3];
  }
}

// ---------------- kernel B: normalize + attn store + PV ---------------------
// = v5 loop2 verbatim, with 1/sum loaded from SIo. 64 KB LDS -> 2 blocks/CU.
__device__ inline char* swzW(char* wb, int row, int col) {
  return wb + row * 256 + ((col * 2) ^ ((row & 7) << 4));
}

__global__ __launch_bounds__(512, 4) void attn_pv(const f16* __restrict__ Qh,
                                                  const f16* __restrict__ Kh,
                                                  const f16* __restrict__ VhT,
                                                  const unsigned* __restrict__ mbits,
                                                  const float* __restrict__ SIo,
                                                  float* __restrict__ attn,
                                                  float* __restrict__ ctx) {
  __shared__ f16 lK[8][128][8];     // 16 KB
  __shared__ f16 lVT[16][64][8];    // 16 KB
  __shared__ char Pw[8 * 4096];     // 32 KB
  const int wg = blockIdx.x;
  const int bh = ((wg & 7) << 2) | (wg >> 7);    // 16 blocks/bh on ONE XCD
  const int qg = (wg >> 3) & 15;
  const int b = bh >> 4, h = bh & 15;
  const int t = threadIdx.x, w = t >> 6, l = t & 63;
  const int lr = l & 15, lg = l >> 4;
  const int qr = qg * 128 + w * 16;
  char* wb = Pw + w * 4096;

  const int pA = t * 16, pB = 8192 + t * 16;
  const int ksA = pA >> 11, rwA = (pA >> 4) & 127;
  const int ksB = pB >> 11, rwB = (pB >> 4) & 127;
  const int vsA = pA >> 10, vdA = (pA >> 4) & 63;
  const int vsB = pB >> 10, vdB = (pB >> 4) & 63;
  const f16* Kbase = Kh + ((size_t)bh << 17);
  const f16* Vbase = VhT + ((size_t)bh << 17);

  const f16* qp = Qh + (((size_t)bh * 2048 + qr + lr) << 6) + lg * 8;
  const f16x8 aq0 = *(const f16x8*)qp;
  const f16x8 aq1 = *(const f16x8*)(qp + 32);
  const unsigned* mrow0 = mbits + ((size_t)b * 2048 + qr + lg * 4) * 64;

  float SI[4];
#pragma unroll
  for (int j = 0; j < 4; j++) SI[j] = SIo[((size_t)bh << 11) + qr + lg * 4 + j];

  f32x4 acc[4] = {};
  f16x8 kra = *(const f16x8*)(Kbase + ((size_t)rwA << 6) + ksA * 8);
  f16x8 krb = *(const f16x8*)(Kbase + ((size_t)rwB << 6) + ksB * 8);
  f16x8 vra = *(const f16x8*)(Vbase + ((size_t)vdA << 11) + vsA * 8);
  f16x8 vrb = *(const f16x8*)(Vbase + ((size_t)vdB << 11) + vsB * 8);
  float* abase = attn + (((size_t)bh * 2048 + qr) << 11);   // [16 rows][2048]
  const int srow = l >> 3, scol = (l & 7) * 4;              // 8 lanes/row stores
  for (int t16 = 0; t16 < 16; t16++) {
    const int kb = t16 * 128;
    __syncthreads();
    *(f16x8*)((char*)lK + pA) = kra;
    *(f16x8*)((char*)lK + pB) = krb;
    *(f16x8*)((char*)lVT + pA) = vra;
    *(f16x8*)((char*)lVT + pB) = vrb;
    __syncthreads();
    uint4 mrow[4];
#pragma unroll
    for (int j = 0; j < 4; j++) mrow[j] = *(const uint4*)(mrow0 + j * 64 + (kb >> 5));
    if (t16 < 15) {
      const f16* nk = Kbase + ((size_t)(kb + 128) << 6);
      kra = *(const f16x8*)(nk + ((size_t)rwA << 6) + ksA * 8);
      krb = *(const f16x8*)(nk + ((size_t)rwB << 6) + ksB * 8);
      const f16* nv = Vbase + kb + 128;
      vra = *(const f16x8*)(nv + ((size_t)vdA << 11) + vsA * 8);
      vrb = *(const f16x8*)(nv + ((size_t)vdB << 11) + vsB * 8);
    }
#pragma unroll
    for (int nf = 0; nf < 8; nf++) {
      f32x4 s4 = {};
      s4 = __builtin_amdgcn_mfma_f32_16x16x32_f16(aq0, *(const f16x8*)&lK[lg][nf * 16 + lr][0], s4, 0, 0, 0);
      s4 = __builtin_amdgcn_mfma_f32_16x16x32_f16(aq1, *(const f16x8*)&lK[4 + lg][nf * 16 + lr][0], s4, 0, 0, 0);
      const unsigned bp = ((nf & 1) << 4) + lr;
#pragma unroll
      for (int j = 0; j < 4; j++) {
        const unsigned bit = (((const unsigned*)&mrow[j])[nf >> 1] >> bp) & 1u;
        const float pj = bit ? __expf(s4[j]) * SI[j] : 0.f;
        *(f16*)swzW(wb, lg * 4 + j, nf * 16 + lr) = (f16)pj;
      }
    }
    // PV on this tile (wave-private P; compiler orders LDS RAW via lgkmcnt)
#pragma unroll
    for (int kk = 0; kk < 4; kk++) {
      const f16x8 pa = *(const f16x8*)swzW(wb, lr, kk * 32 + lg * 8);
#pragma unroll
      for (int nf = 0; nf < 4; nf++)
        acc[nf] = __builtin_amdgcn_mfma_f32_16x16x32_f16(pa, *(const f16x8*)&lVT[kk * 4 + lg][nf * 16 + lr][0], acc[nf], 0, 0, 0);
    }
    // attn stores: readback P, f32x4; 8 lanes span 128B contiguous per row.
    // Issued after this tile's (older) prefetch loads -> next tile's staging
    // wait never drains these stores (vmcnt FIFO).
#pragma unroll
    for (int h2 = 0; h2 < 2; h2++) {
      const int row = srow + h2 * 8;
      float* arow = abase + ((size_t)row << 11) + kb + scol;
#pragma unroll
      for (int u = 0; u < 4; u++) {
        const f16x4 p4 = *(const f16x4*)swzW(wb, row, scol + u * 32);
        f32x4 o;
#pragma unroll
        for (int e = 0; e < 4; e++) o[e] = (float)p4[e];
        *(f32x4*)(arow + u * 32) = o;
      }
    }
  }

  // ctx write: rows qr+lg*4+j, cols h*64 + nf*16+lr
#pragma unroll
  for (int nf = 0; nf < 4; nf++)
#pragma unroll
    for (int j = 0; j < 4; j++)
      ctx[((size_t)b * 2048 + qr + lg * 4 + j) * 1024 + h * 64 + nf * 16 + lr] = acc[nf][j];
}

// ---------------- residual + LayerNorm (in place on d_out) ------------------
__global__ __launch_bounds__(256) void ln_res(const float* __restrict__ qres,
                                              const float* __restrict__ gamma,
                                              const float* __restrict__ beta,
                                              float* __restrict__ io) {
  const int tok = blockIdx.x;
  const int t = threadIdx.x;
  float* rowp = io + (size_t)tok * 1024;
  const float* qp = qres + (size_t)tok * 1024;
  const f32x4 c = *(const f32x4*)(rowp + t * 4);
  const f32x4 r = *(const f32x4*)(qp + t * 4);
  f32x4 vals;
  float s = 0.f, s2 = 0.f;
#pragma unroll
  for (int e = 0; e < 4; e++) { float x = c[e] + r[e]; vals[e] = x; s += x; s2 += x * x; }
#pragma unroll
  for (int o = 1; o < 64; o <<= 1) { s += __shfl_xor(s, o, 64); s2 += __shfl_xor(s2, o, 64); }
  __shared__ float rs[4][2];
  const int w = t >> 6;
  if ((t & 63) == 0) { rs[w][0] = s; rs[w][1] = s2; }
  __syncthreads();
  s  = rs[0][0] + rs[1][0] + rs[2][0] + rs[3][0];
  s2 = rs[0][1] + rs[1][1] + rs[2][1] + rs[3][1];
  const float mu = s * (1.f / 1024.f);
  const float var = s2 * (1.f / 1024.f) - mu * mu;
  const float rstd = rsqrtf(var + 1e-6f);
  const f32x4 g  = *(const f32x4*)(gamma + t * 4);
  const f32x4 be = *(const f32x4*)(beta + t * 4);
  f32x4 o;
#pragma unroll
  for (int e = 0; e < 4; e++) o[e] = (vals[e] - mu) * rstd * g[e] + be[e];
  *(f32x4*)(rowp + t * 4) = o;
}

// ---------------- host ------------------------------------------------------
extern "C" void kernel_launch(void* const* d_in, const int* in_sizes, int n_in,
                              void* d_out, int out_size, void* d_ws, size_t ws_size,
                              hipStream_t stream) {
  const float* q     = (const float*)d_in[0];
  const float* k     = (const float*)d_in[1];
  const float* v     = (const float*)d_in[2];
  const int*   mask  = (const int*)d_in[3];
  const float* Wq    = (const float*)d_in[4];
  const float* Wk    = (const float*)d_in[5];
  const float* Wv    = (const float*)d_in[6];
  const float* gamma = (const float*)d_in[7];
  const float* beta  = (const float*)d_in[8];
  float* out  = (float*)d_out;
  float* attn = out + (size_t)4194304;       // B*S*H
  const size_t MB = 1u << 20;
  char* ws = (char*)d_ws;

  f16 *x16, *W16, *Qh, *Kh, *Vn, *VhT; unsigned* mb; float* SIo;
  if (ws_size >= 65 * MB) {
    x16 = (f16*)ws;              W16 = (f16*)(ws + 24 * MB);
    Qh  = (f16*)(ws + 30 * MB);  Kh  = (f16*)(ws + 38 * MB);
    Vn  = (f16*)(ws + 46 * MB);  VhT = (f16*)(ws + 54 * MB);
    mb  = (unsigned*)(ws + 62 * MB);
    SIo = (float*)(ws + 63 * MB);
  } else {
    // stage f16 inputs + Vn in the (not-yet-written) attn region of d_out
    x16 = (f16*)attn;            W16 = (f16*)((char*)attn + 24 * MB);
    Vn  = (f16*)((char*)attn + 30 * MB);
    Qh  = (f16*)ws;              Kh  = (f16*)(ws + 8 * MB);
    VhT = (f16*)(ws + 16 * MB);  mb  = (unsigned*)(ws + 24 * MB);
    SIo = (float*)(ws + 25 * MB);
  }

  cvt3<<<dim3(4096, 3), 256, 0, stream>>>(q, k, v, x16, 4194304);
  cvt3<<<dim3(1024, 3), 256, 0, stream>>>(Wq, Wk, Wv, W16, 1048576);
  pack_mask<<<dim3(32768), 256, 0, stream>>>(mask, mb);
  gemm_proj<<<dim3(8, 32, 3), 256, 0, stream>>>(x16, W16, Qh, Kh, Vn);
  transposeV<<<dim3(32, 32), 512, 0, stream>>>(Vn, VhT);
  sumexp_k<<<dim3(512), 512, 0, stream>>>(Qh, Kh, mb, SIo);
  attn_pv<<<dim3(512), 512, 0, stream>>>(Qh, Kh, VhT, mb, SIo, attn, out);
  ln_res<<<dim3(4096), 256, 0, stream>>>(q, gamma, beta, out);
}